// Round 14
// baseline (181.765 us; speedup 1.0000x reference)
//
#include <hip/hip_runtime.h>

#define N_NODES 50000
#define N_EDGES 400000
#define DIM 160
#define NB 64
#define CUTOFF 5.0f
#define LN_EPS 1e-5f
#define PI_F 3.14159265358979323846f

// Padded CSR: stride-64 slot list per destination node.
#define SLOT_STRIDE 64
// deg padded to one counter per 32B (2 per 64B line).
#define DEG_STRIDE 8

// Workspace (ints), total 3,800,272 ints = 14.50 MiB:
#define WS_DEG   16
#define WS_PKT   (WS_DEG + N_NODES * DEG_STRIDE)   // 400016
#define WS_POS4  (WS_PKT + 4 * NB)                 // 400272
#define WS_ESRC  (WS_POS4 + 4 * N_NODES)           // 600272

// ---------------------------------------------------------------------------
// K0: prep (unchanged).
// ---------------------------------------------------------------------------
__global__ __launch_bounds__(256) void prep(
    const float* __restrict__ pos, const float* __restrict__ centers,
    const float* __restrict__ widths, const float* __restrict__ proj_w,
    int* __restrict__ degp, float4* __restrict__ pkt,
    float4* __restrict__ pos4, float* __restrict__ ew_accum)
{
    const int i = blockIdx.x * blockDim.x + threadIdx.x;
    if (i < 16) ((int*)ew_accum)[i] = 0;
    if (i < NB)
        pkt[i] = make_float4(centers[i], 1.0f / widths[i], proj_w[i], 0.0f);
    if (i < N_NODES) {
        const int4 z4 = make_int4(0, 0, 0, 0);
        ((int4*)(degp))[2 * i]     = z4;
        ((int4*)(degp))[2 * i + 1] = z4;
        pos4[i] = make_float4(pos[3 * i], pos[3 * i + 1], pos[3 * i + 2], 0.0f);
    }
}

// ---------------------------------------------------------------------------
// K1: hist_ew_fill (unchanged).
// ---------------------------------------------------------------------------
#define EPT 4

__global__ __launch_bounds__(256) void hist_ew_fill(
    const int* __restrict__ ei, const float4* __restrict__ pos4,
    const float4* __restrict__ pkt, const float* __restrict__ proj_b,
    int* __restrict__ degp, int* __restrict__ esrc, float* __restrict__ ew_accum)
{
    const float bias = proj_b[0];
    const int base = blockIdx.x * (256 * EPT) + threadIdx.x;

    int  s[EPT], d[EPT], slot[EPT];
    bool v[EPT];
    #pragma unroll
    for (int k = 0; k < EPT; ++k) {
        const int e = base + 256 * k;
        v[k] = (e < N_EDGES);
        s[k] = v[k] ? ei[e] : 0;
        d[k] = v[k] ? ei[N_EDGES + e] : 0;
    }

    #pragma unroll
    for (int k = 0; k < EPT; ++k)
        slot[k] = v[k] ? atomicAdd(&degp[(long)d[k] * DEG_STRIDE], 1) : 0;

    float4 ps[EPT], pd[EPT];
    #pragma unroll
    for (int k = 0; k < EPT; ++k) { ps[k] = pos4[s[k]]; pd[k] = pos4[d[k]]; }

    #pragma unroll
    for (int k = 0; k < EPT; ++k)
        if (v[k] && slot[k] < SLOT_STRIDE)
            esrc[((long)d[k] << 6) + slot[k]] = s[k];

    float dist[EPT];
    #pragma unroll
    for (int k = 0; k < EPT; ++k) {
        const float dx = ps[k].x - pd[k].x;
        const float dy = ps[k].y - pd[k].y;
        const float dz = ps[k].z - pd[k].z;
        dist[k] = sqrtf(dx * dx + dy * dy + dz * dz);
    }

    float z[EPT] = {0.f, 0.f, 0.f, 0.f};
    #pragma unroll 4
    for (int b = 0; b < NB; ++b) {
        const float4 t4 = pkt[b];
        #pragma unroll
        for (int k = 0; k < EPT; ++k) {
            const float t = (dist[k] - t4.x) * t4.y;
            z[k] = fmaf(__expf(-0.5f * t * t), t4.z, z[k]);
        }
    }

    float sig = 0.0f;
    #pragma unroll
    for (int k = 0; k < EPT; ++k) {
        if (v[k]) {
            const float cut = (dist[k] <= CUTOFF)
                            ? 0.5f * (__cosf(PI_F * dist[k] * (1.0f / CUTOFF)) + 1.0f)
                            : 0.0f;
            sig += 1.0f / (1.0f + __expf(-(z[k] * cut + bias)));
        }
    }

    #pragma unroll
    for (int off = 32; off > 0; off >>= 1) sig += __shfl_xor(sig, off);
    __shared__ float red[4];
    if ((threadIdx.x & 63) == 0) red[threadIdx.x >> 6] = sig;
    __syncthreads();
    if (threadIdx.x == 0)
        atomicAdd(ew_accum, red[0] + red[1] + red[2] + red[3]);
}

// ---------------------------------------------------------------------------
// K2: FUSED gather + transform, DEEP-MLP variant. Round 13 hit 57.5 us but
// only 2.7 TB/s serve (split gather did 3.65): in-wave transform sections
// cut average outstanding loads. Fix: gather ALL 4 nodes per wave up front,
// with each node PAIR lockstep-masked (one j-loop to max(cntA,cntB), 16
// dwordx4 in flight; OOB slots clamp to row 0 = L2-hot, accumulate gated by
// fmaf masks). Then two transform passes (round-13 lane-half mapping), and
// only the FINAL rows go to global.
// LDS = 16384 + 4096 + 10240 = 30720 B -> 5 blocks/CU.
// ---------------------------------------------------------------------------
#define TNODES 16

__global__ __launch_bounds__(256) void gather_node(
    const float* __restrict__ x, const int* __restrict__ degp,
    const int* __restrict__ esrc, float* __restrict__ out,
    const float* __restrict__ W0, const float* __restrict__ W1,
    const float* __restrict__ ln_gamma, const float* __restrict__ ln_beta,
    const float* __restrict__ ew_accum)
{
    __shared__ float sW0[64 * 64];
    __shared__ float sW1[32 * 32];
    __shared__ float sRow[4][4][160];    // per-wave: 4 staged rows

    const int t    = threadIdx.x;
    const int lane = t & 63;
    const int w    = t >> 6;                 // wave 0..3
    const int node0 = blockIdx.x * TNODES;
    const int nbase = node0 + 4 * w;

    // ---- stage weights to LDS, single barrier ----
    {
        const float4* w04 = (const float4*)W0;   // 1024 float4
        float4* s04 = (float4*)sW0;
        #pragma unroll
        for (int i = 0; i < 4; ++i) s04[t + 256 * i] = w04[t + 256 * i];
        ((float4*)sW1)[t] = ((const float4*)W1)[t];
    }
    __syncthreads();

    const float ew   = ew_accum[0] * (1.0f / 400000.0f);
    const float s_m0 = ew * 0.125f;                 // / sqrt(64)
    const float s_m1 = ew * 0.17677669529663687f;   // / sqrt(32)

    // ---- gather setup: 4 slot-lines + 4 degs issue together ----
    int sv[4], cnt[4];
    #pragma unroll
    for (int k = 0; k < 4; ++k) {
        const int n = nbase + k;
        const long nc = (n < N_NODES) ? n : 0;
        sv[k]  = esrc[(nc << 6) + lane];
        cnt[k] = (n < N_NODES) ? min(degp[nc * DEG_STRIDE], SLOT_STRIDE) : 0;
    }

    float4 acc[4];
    #pragma unroll
    for (int k = 0; k < 4; ++k) acc[k] = make_float4(0.f, 0.f, 0.f, 0.f);

    // ---- lockstep-masked pair gather: 16 loads in flight per chunk ----
    #define GPAIR(kA, kB)                                                      \
    {                                                                          \
        const int mx = max(cnt[kA], cnt[kB]);                                  \
        for (int j = 0; j < mx; j += 8) {                                      \
            int   sa[8], sb[8];                                                \
            float ma[8], mb[8];                                                \
            _Pragma("unroll")                                                  \
            for (int i = 0; i < 8; ++i) {                                      \
                const bool va = (j + i) < cnt[kA];                             \
                const bool vb = (j + i) < cnt[kB];                             \
                const int ra = __shfl(sv[kA], j + i);                          \
                const int rb = __shfl(sv[kB], j + i);                          \
                sa[i] = va ? ra : 0;                                           \
                sb[i] = vb ? rb : 0;                                           \
                ma[i] = va ? 1.0f : 0.0f;                                      \
                mb[i] = vb ? 1.0f : 0.0f;                                      \
            }                                                                  \
            if (lane < 40) {                                                   \
                float4 va4[8], vb4[8];                                         \
                _Pragma("unroll")                                              \
                for (int i = 0; i < 8; ++i)                                    \
                    va4[i] = ((const float4*)(x + (long)sa[i] * DIM))[lane];   \
                _Pragma("unroll")                                              \
                for (int i = 0; i < 8; ++i)                                    \
                    vb4[i] = ((const float4*)(x + (long)sb[i] * DIM))[lane];   \
                _Pragma("unroll")                                              \
                for (int i = 0; i < 8; ++i) {                                  \
                    acc[kA].x = fmaf(ma[i], va4[i].x, acc[kA].x);              \
                    acc[kA].y = fmaf(ma[i], va4[i].y, acc[kA].y);              \
                    acc[kA].z = fmaf(ma[i], va4[i].z, acc[kA].z);              \
                    acc[kA].w = fmaf(ma[i], va4[i].w, acc[kA].w);              \
                    acc[kB].x = fmaf(mb[i], vb4[i].x, acc[kB].x);              \
                    acc[kB].y = fmaf(mb[i], vb4[i].y, acc[kB].y);              \
                    acc[kB].z = fmaf(mb[i], vb4[i].z, acc[kB].z);              \
                    acc[kB].w = fmaf(mb[i], vb4[i].w, acc[kB].w);              \
                }                                                              \
            }                                                                  \
        }                                                                      \
    }
    GPAIR(0, 1)
    GPAIR(2, 3)
    #undef GPAIR

    // ---- stage all 4 rows to this wave's private LDS ----
    if (lane < 40) {
        #pragma unroll
        for (int k = 0; k < 4; ++k)
            *(float4*)(&sRow[w][k][4 * lane]) = acc[k];
    }
    // same-wave ds_write -> ds_read: lgkmcnt-ordered; no barrier.

    const int half = lane >> 5;          // 0/1 within the wave
    const int l    = lane & 31;

    #pragma unroll 1
    for (int pass = 0; pass < 2; ++pass) {
        const int  node  = nbase + 2 * pass + half;
        const bool valid = node < N_NODES;
        float* grow = out + (long)(valid ? node : 0) * DIM;
        const float* row = &sRow[w][2 * pass + half][0];

        // ---------- scalar channel: lane -> outputs 2l, 2l+1 ----------
        {
            float a0 = 0.f, a1 = 0.f;
            #pragma unroll 4
            for (int k0 = 0; k0 < 64; k0 += 4) {
                const float4 a = *(const float4*)(row + k0);          // bcast
                const float2 q0 = *(const float2*)(sW0 + (k0 + 0) * 64 + 2 * l);
                const float2 q1 = *(const float2*)(sW0 + (k0 + 1) * 64 + 2 * l);
                const float2 q2 = *(const float2*)(sW0 + (k0 + 2) * 64 + 2 * l);
                const float2 q3 = *(const float2*)(sW0 + (k0 + 3) * 64 + 2 * l);
                a0 = fmaf(a.x, q0.x, fmaf(a.y, q1.x, fmaf(a.z, q2.x, fmaf(a.w, q3.x, a0))));
                a1 = fmaf(a.x, q0.y, fmaf(a.y, q1.y, fmaf(a.z, q2.y, fmaf(a.w, q3.y, a1))));
            }
            a0 *= s_m0;
            a1 *= s_m0;

            float sum = a0 + a1;
            float ssq = fmaf(a0, a0, a1 * a1);
            #pragma unroll
            for (int m = 1; m <= 16; m <<= 1) {       // within 32-lane half
                sum += __shfl_xor(sum, m);
                ssq += __shfl_xor(ssq, m);
            }

            if (valid) {
                const float mu   = sum * (1.0f / 64.0f);
                const float var  = ssq * (1.0f / 64.0f) - mu * mu;
                const float rstd = rsqrtf(var + LN_EPS);
                const float2 g = *(const float2*)(ln_gamma + 2 * l);
                const float2 b = *(const float2*)(ln_beta  + 2 * l);
                const float t0 = (a0 - mu) * rstd * g.x + b.x;
                const float t1 = (a1 - mu) * rstd * g.y + b.y;
                float2 o;
                o.x = t0 / (1.0f + __expf(-t0));
                o.y = t1 / (1.0f + __expf(-t1));
                *(float2*)(grow + 2 * l) = o;
            }
        }

        // ---------- vector channel: lane -> channel l ----------
        {
            const float* vrow = row + 64;
            float o0 = 0.f, o1 = 0.f, o2 = 0.f;
            #pragma unroll 2
            for (int g = 0; g < 8; ++g) {            // cp = 4g + r
                const float4 v0 = *(const float4*)(vrow + 12 * g);       // bcast
                const float4 v1 = *(const float4*)(vrow + 12 * g + 4);
                const float4 v2 = *(const float4*)(vrow + 12 * g + 8);
                const float a[12] = { v0.x, v0.y, v0.z, v0.w,
                                      v1.x, v1.y, v1.z, v1.w,
                                      v2.x, v2.y, v2.z, v2.w };
                #pragma unroll
                for (int r = 0; r < 4; ++r) {
                    const float wc = sW1[(4 * g + r) * 32 + l];   // conflict-free
                    o0 = fmaf(wc, a[3 * r],     o0);
                    o1 = fmaf(wc, a[3 * r + 1], o1);
                    o2 = fmaf(wc, a[3 * r + 2], o2);
                }
            }
            if (valid) {
                float* vo = grow + 64 + 3 * l;
                vo[0] = o0 * s_m1;
                vo[1] = o1 * s_m1;
                vo[2] = o2 * s_m1;
            }
        }
    }
}

extern "C" void kernel_launch(void* const* d_in, const int* in_sizes, int n_in,
                              void* d_out, int out_size, void* d_ws, size_t ws_size,
                              hipStream_t stream) {
    const float* x       = (const float*)d_in[0];
    const float* pos     = (const float*)d_in[1];
    const int*   ei      = (const int*)d_in[2];
    const float* W0      = (const float*)d_in[4];
    const float* W1      = (const float*)d_in[5];
    const float* centers = (const float*)d_in[6];
    const float* widths  = (const float*)d_in[7];
    const float* proj_w  = (const float*)d_in[8];
    const float* proj_b  = (const float*)d_in[9];
    const float* gamma   = (const float*)d_in[10];
    const float* beta    = (const float*)d_in[11];

    float* out  = (float*)d_out;
    int*   wsi  = (int*)d_ws;
    float* ew   = (float*)d_ws;
    int*   degp = wsi + WS_DEG;
    float4* pkt  = (float4*)(wsi + WS_PKT);
    float4* pos4 = (float4*)(wsi + WS_POS4);
    int*   esrc = wsi + WS_ESRC;

    const int pb = (N_NODES + 255) / 256;
    prep<<<pb, 256, 0, stream>>>(pos, centers, widths, proj_w, degp, pkt, pos4, ew);

    const int eb = (N_EDGES + 256 * EPT - 1) / (256 * EPT);   // 391
    hist_ew_fill<<<eb, 256, 0, stream>>>(ei, pos4, pkt, proj_b, degp, esrc, ew);

    const int tiles = (N_NODES + TNODES - 1) / TNODES;   // 3125
    gather_node<<<tiles, 256, 0, stream>>>(x, degp, esrc, out,
                                           W0, W1, gamma, beta, ew);
}

// Round 15
// 178.297 us; speedup vs baseline: 1.0195x; 1.0195x over previous
//
#include <hip/hip_runtime.h>

#define N_NODES 50000
#define N_EDGES 400000
#define DIM 160
#define NB 64
#define CUTOFF 5.0f
#define LN_EPS 1e-5f
#define PI_F 3.14159265358979323846f

// Padded CSR: stride-64 slot list per destination node.
#define SLOT_STRIDE 64
// deg padded to one counter per 32B (2 per 64B line).
#define DEG_STRIDE 8

// Workspace (ints), total 3,800,272 ints = 14.50 MiB:
#define WS_DEG   16
#define WS_PKT   (WS_DEG + N_NODES * DEG_STRIDE)   // 400016
#define WS_POS4  (WS_PKT + 4 * NB)                 // 400272
#define WS_ESRC  (WS_POS4 + 4 * N_NODES)           // 600272

// ---------------------------------------------------------------------------
// K0: prep (unchanged).
// ---------------------------------------------------------------------------
__global__ __launch_bounds__(256) void prep(
    const float* __restrict__ pos, const float* __restrict__ centers,
    const float* __restrict__ widths, const float* __restrict__ proj_w,
    int* __restrict__ degp, float4* __restrict__ pkt,
    float4* __restrict__ pos4, float* __restrict__ ew_accum)
{
    const int i = blockIdx.x * blockDim.x + threadIdx.x;
    if (i < 16) ((int*)ew_accum)[i] = 0;
    if (i < NB)
        pkt[i] = make_float4(centers[i], 1.0f / widths[i], proj_w[i], 0.0f);
    if (i < N_NODES) {
        const int4 z4 = make_int4(0, 0, 0, 0);
        ((int4*)(degp))[2 * i]     = z4;
        ((int4*)(degp))[2 * i + 1] = z4;
        pos4[i] = make_float4(pos[3 * i], pos[3 * i + 1], pos[3 * i + 2], 0.0f);
    }
}

// ---------------------------------------------------------------------------
// K1: hist_ew_fill (unchanged).
// ---------------------------------------------------------------------------
#define EPT 4

__global__ __launch_bounds__(256) void hist_ew_fill(
    const int* __restrict__ ei, const float4* __restrict__ pos4,
    const float4* __restrict__ pkt, const float* __restrict__ proj_b,
    int* __restrict__ degp, int* __restrict__ esrc, float* __restrict__ ew_accum)
{
    const float bias = proj_b[0];
    const int base = blockIdx.x * (256 * EPT) + threadIdx.x;

    int  s[EPT], d[EPT], slot[EPT];
    bool v[EPT];
    #pragma unroll
    for (int k = 0; k < EPT; ++k) {
        const int e = base + 256 * k;
        v[k] = (e < N_EDGES);
        s[k] = v[k] ? ei[e] : 0;
        d[k] = v[k] ? ei[N_EDGES + e] : 0;
    }

    #pragma unroll
    for (int k = 0; k < EPT; ++k)
        slot[k] = v[k] ? atomicAdd(&degp[(long)d[k] * DEG_STRIDE], 1) : 0;

    float4 ps[EPT], pd[EPT];
    #pragma unroll
    for (int k = 0; k < EPT; ++k) { ps[k] = pos4[s[k]]; pd[k] = pos4[d[k]]; }

    #pragma unroll
    for (int k = 0; k < EPT; ++k)
        if (v[k] && slot[k] < SLOT_STRIDE)
            esrc[((long)d[k] << 6) + slot[k]] = s[k];

    float dist[EPT];
    #pragma unroll
    for (int k = 0; k < EPT; ++k) {
        const float dx = ps[k].x - pd[k].x;
        const float dy = ps[k].y - pd[k].y;
        const float dz = ps[k].z - pd[k].z;
        dist[k] = sqrtf(dx * dx + dy * dy + dz * dz);
    }

    float z[EPT] = {0.f, 0.f, 0.f, 0.f};
    #pragma unroll 4
    for (int b = 0; b < NB; ++b) {
        const float4 t4 = pkt[b];
        #pragma unroll
        for (int k = 0; k < EPT; ++k) {
            const float t = (dist[k] - t4.x) * t4.y;
            z[k] = fmaf(__expf(-0.5f * t * t), t4.z, z[k]);
        }
    }

    float sig = 0.0f;
    #pragma unroll
    for (int k = 0; k < EPT; ++k) {
        if (v[k]) {
            const float cut = (dist[k] <= CUTOFF)
                            ? 0.5f * (__cosf(PI_F * dist[k] * (1.0f / CUTOFF)) + 1.0f)
                            : 0.0f;
            sig += 1.0f / (1.0f + __expf(-(z[k] * cut + bias)));
        }
    }

    #pragma unroll
    for (int off = 32; off > 0; off >>= 1) sig += __shfl_xor(sig, off);
    __shared__ float red[4];
    if ((threadIdx.x & 63) == 0) red[threadIdx.x >> 6] = sig;
    __syncthreads();
    if (threadIdx.x == 0)
        atomicAdd(ew_accum, red[0] + red[1] + red[2] + red[3]);
}

// ---------------------------------------------------------------------------
// K2: FUSED gather + transform — round-13 body (proven 57.5 us, minimal
// 153 MB traffic, no barrier convoy) re-hosted in 512-THREAD / 8-WAVE blocks.
// The 20 KB weight LDS is a per-block fixed cost; amortizing it over 8 waves
// raises the thread-residency cap from 1536/2048 (6 blocks x 256) to
// 2048/2048 (4 blocks x 512): +33% wave budget for the latency-bound gather.
// Each wave owns ONE node pair; gather and transform bodies are byte-for-
// byte round 13's (masked-lockstep of round 14 reverted: it regressed).
// LDS = 16384 + 4096 + 10240 = 30720 B. One barrier (weights).
// ---------------------------------------------------------------------------
#define TNODES 16

__global__ __launch_bounds__(512) void gather_node(
    const float* __restrict__ x, const int* __restrict__ degp,
    const int* __restrict__ esrc, float* __restrict__ out,
    const float* __restrict__ W0, const float* __restrict__ W1,
    const float* __restrict__ ln_gamma, const float* __restrict__ ln_beta,
    const float* __restrict__ ew_accum)
{
    __shared__ float sW0[64 * 64];
    __shared__ float sW1[32 * 32];
    __shared__ float sRow[8][2][160];    // per-wave pair staging

    const int t    = threadIdx.x;
    const int lane = t & 63;
    const int w    = t >> 6;                 // wave 0..7
    const int node0 = blockIdx.x * TNODES;

    // ---- stage weights to LDS (512 threads: 2 float4 of W0 each) ----
    {
        const float4* w04 = (const float4*)W0;   // 1024 float4
        float4* s04 = (float4*)sW0;
        s04[t]       = w04[t];
        s04[t + 512] = w04[t + 512];
        if (t < 256) ((float4*)sW1)[t] = ((const float4*)W1)[t];
    }
    __syncthreads();

    const float ew   = ew_accum[0] * (1.0f / 400000.0f);
    const float s_m0 = ew * 0.125f;                 // / sqrt(64)
    const float s_m1 = ew * 0.17677669529663687f;   // / sqrt(32)

    const int half = lane >> 5;          // 0 = node A, 1 = node B
    const int l    = lane & 31;

    // ---- gather: wave w owns the pair (node0+2w, node0+2w+1) ----
    const int nA  = node0 + 2 * w;
    const int nB  = nA + 1;
    const long nAc = (nA < N_NODES) ? nA : 0;
    const long nBc = (nB < N_NODES) ? nB : 0;

    const int svA  = esrc[(nAc << 6) + lane];
    const int svB  = esrc[(nBc << 6) + lane];
    const int cntA = (nA < N_NODES) ? min(degp[nAc * DEG_STRIDE], SLOT_STRIDE) : 0;
    const int cntB = (nB < N_NODES) ? min(degp[nBc * DEG_STRIDE], SLOT_STRIDE) : 0;

    float4 aA = make_float4(0.f, 0.f, 0.f, 0.f);
    float4 aB = make_float4(0.f, 0.f, 0.f, 0.f);

    #define GBODY(sv, cnt, acc)                                            \
    {                                                                      \
        int j = 0;                                                         \
        for (; j + 8 <= cnt; j += 8) {                                     \
            const int s0 = __shfl(sv, j);                                  \
            const int s1 = __shfl(sv, j + 1);                              \
            const int s2 = __shfl(sv, j + 2);                              \
            const int s3 = __shfl(sv, j + 3);                              \
            const int s4 = __shfl(sv, j + 4);                              \
            const int s5 = __shfl(sv, j + 5);                              \
            const int s6 = __shfl(sv, j + 6);                              \
            const int s7 = __shfl(sv, j + 7);                              \
            if (lane < 40) {                                               \
                const float4 v0 = ((const float4*)(x + (long)s0 * DIM))[lane]; \
                const float4 v1 = ((const float4*)(x + (long)s1 * DIM))[lane]; \
                const float4 v2 = ((const float4*)(x + (long)s2 * DIM))[lane]; \
                const float4 v3 = ((const float4*)(x + (long)s3 * DIM))[lane]; \
                const float4 v4 = ((const float4*)(x + (long)s4 * DIM))[lane]; \
                const float4 v5 = ((const float4*)(x + (long)s5 * DIM))[lane]; \
                const float4 v6 = ((const float4*)(x + (long)s6 * DIM))[lane]; \
                const float4 v7 = ((const float4*)(x + (long)s7 * DIM))[lane]; \
                acc.x += ((v0.x + v1.x) + (v2.x + v3.x)) + ((v4.x + v5.x) + (v6.x + v7.x)); \
                acc.y += ((v0.y + v1.y) + (v2.y + v3.y)) + ((v4.y + v5.y) + (v6.y + v7.y)); \
                acc.z += ((v0.z + v1.z) + (v2.z + v3.z)) + ((v4.z + v5.z) + (v6.z + v7.z)); \
                acc.w += ((v0.w + v1.w) + (v2.w + v3.w)) + ((v4.w + v5.w) + (v6.w + v7.w)); \
            }                                                              \
        }                                                                  \
        for (; j + 4 <= cnt; j += 4) {                                     \
            const int s0 = __shfl(sv, j);                                  \
            const int s1 = __shfl(sv, j + 1);                              \
            const int s2 = __shfl(sv, j + 2);                              \
            const int s3 = __shfl(sv, j + 3);                              \
            if (lane < 40) {                                               \
                const float4 v0 = ((const float4*)(x + (long)s0 * DIM))[lane]; \
                const float4 v1 = ((const float4*)(x + (long)s1 * DIM))[lane]; \
                const float4 v2 = ((const float4*)(x + (long)s2 * DIM))[lane]; \
                const float4 v3 = ((const float4*)(x + (long)s3 * DIM))[lane]; \
                acc.x += (v0.x + v1.x) + (v2.x + v3.x);                    \
                acc.y += (v0.y + v1.y) + (v2.y + v3.y);                    \
                acc.z += (v0.z + v1.z) + (v2.z + v3.z);                    \
                acc.w += (v0.w + v1.w) + (v2.w + v3.w);                    \
            }                                                              \
        }                                                                  \
        for (; j < cnt; ++j) {                                             \
            const int s0 = __shfl(sv, j);                                  \
            if (lane < 40) {                                               \
                const float4 v0 = ((const float4*)(x + (long)s0 * DIM))[lane]; \
                acc.x += v0.x; acc.y += v0.y; acc.z += v0.z; acc.w += v0.w; \
            }                                                              \
        }                                                                  \
    }
    GBODY(svA, cntA, aA)
    GBODY(svB, cntB, aB)
    #undef GBODY

    // ---- stage the pair to this wave's private LDS slot ----
    if (lane < 40) {
        *(float4*)(&sRow[w][0][4 * lane]) = aA;
        *(float4*)(&sRow[w][1][4 * lane]) = aB;
    }
    // same-wave ds_write -> ds_read: compiler lgkmcnt orders; no barrier.

    const int  node  = node0 + 2 * w + half;
    const bool valid = node < N_NODES;
    float* grow = out + (long)(valid ? node : 0) * DIM;
    const float* row = &sRow[w][half][0];

    // ---------- scalar channel: lane -> outputs 2l, 2l+1 ----------
    {
        float a0 = 0.f, a1 = 0.f;
        #pragma unroll 4
        for (int k0 = 0; k0 < 64; k0 += 4) {
            const float4 a = *(const float4*)(row + k0);          // bcast
            const float2 q0 = *(const float2*)(sW0 + (k0 + 0) * 64 + 2 * l);
            const float2 q1 = *(const float2*)(sW0 + (k0 + 1) * 64 + 2 * l);
            const float2 q2 = *(const float2*)(sW0 + (k0 + 2) * 64 + 2 * l);
            const float2 q3 = *(const float2*)(sW0 + (k0 + 3) * 64 + 2 * l);
            a0 = fmaf(a.x, q0.x, fmaf(a.y, q1.x, fmaf(a.z, q2.x, fmaf(a.w, q3.x, a0))));
            a1 = fmaf(a.x, q0.y, fmaf(a.y, q1.y, fmaf(a.z, q2.y, fmaf(a.w, q3.y, a1))));
        }
        a0 *= s_m0;
        a1 *= s_m0;

        float sum = a0 + a1;
        float ssq = fmaf(a0, a0, a1 * a1);
        #pragma unroll
        for (int m = 1; m <= 16; m <<= 1) {       // within 32-lane half
            sum += __shfl_xor(sum, m);
            ssq += __shfl_xor(ssq, m);
        }

        if (valid) {
            const float mu   = sum * (1.0f / 64.0f);
            const float var  = ssq * (1.0f / 64.0f) - mu * mu;
            const float rstd = rsqrtf(var + LN_EPS);
            const float2 g = *(const float2*)(ln_gamma + 2 * l);
            const float2 b = *(const float2*)(ln_beta  + 2 * l);
            const float t0 = (a0 - mu) * rstd * g.x + b.x;
            const float t1 = (a1 - mu) * rstd * g.y + b.y;
            float2 o;
            o.x = t0 / (1.0f + __expf(-t0));
            o.y = t1 / (1.0f + __expf(-t1));
            *(float2*)(grow + 2 * l) = o;
        }
    }

    // ---------- vector channel: lane -> channel l ----------
    {
        const float* vrow = row + 64;
        float o0 = 0.f, o1 = 0.f, o2 = 0.f;
        #pragma unroll 2
        for (int g = 0; g < 8; ++g) {            // cp = 4g + r
            const float4 v0 = *(const float4*)(vrow + 12 * g);       // bcast
            const float4 v1 = *(const float4*)(vrow + 12 * g + 4);
            const float4 v2 = *(const float4*)(vrow + 12 * g + 8);
            const float a[12] = { v0.x, v0.y, v0.z, v0.w,
                                  v1.x, v1.y, v1.z, v1.w,
                                  v2.x, v2.y, v2.z, v2.w };
            #pragma unroll
            for (int r = 0; r < 4; ++r) {
                const float wc = sW1[(4 * g + r) * 32 + l];   // conflict-free
                o0 = fmaf(wc, a[3 * r],     o0);
                o1 = fmaf(wc, a[3 * r + 1], o1);
                o2 = fmaf(wc, a[3 * r + 2], o2);
            }
        }
        if (valid) {
            float* vo = grow + 64 + 3 * l;
            vo[0] = o0 * s_m1;
            vo[1] = o1 * s_m1;
            vo[2] = o2 * s_m1;
        }
    }
}

extern "C" void kernel_launch(void* const* d_in, const int* in_sizes, int n_in,
                              void* d_out, int out_size, void* d_ws, size_t ws_size,
                              hipStream_t stream) {
    const float* x       = (const float*)d_in[0];
    const float* pos     = (const float*)d_in[1];
    const int*   ei      = (const int*)d_in[2];
    const float* W0      = (const float*)d_in[4];
    const float* W1      = (const float*)d_in[5];
    const float* centers = (const float*)d_in[6];
    const float* widths  = (const float*)d_in[7];
    const float* proj_w  = (const float*)d_in[8];
    const float* proj_b  = (const float*)d_in[9];
    const float* gamma   = (const float*)d_in[10];
    const float* beta    = (const float*)d_in[11];

    float* out  = (float*)d_out;
    int*   wsi  = (int*)d_ws;
    float* ew   = (float*)d_ws;
    int*   degp = wsi + WS_DEG;
    float4* pkt  = (float4*)(wsi + WS_PKT);
    float4* pos4 = (float4*)(wsi + WS_POS4);
    int*   esrc = wsi + WS_ESRC;

    const int pb = (N_NODES + 255) / 256;
    prep<<<pb, 256, 0, stream>>>(pos, centers, widths, proj_w, degp, pkt, pos4, ew);

    const int eb = (N_EDGES + 256 * EPT - 1) / (256 * EPT);   // 391
    hist_ew_fill<<<eb, 256, 0, stream>>>(ei, pos4, pkt, proj_b, degp, esrc, ew);

    const int tiles = (N_NODES + TNODES - 1) / TNODES;   // 3125
    gather_node<<<tiles, 512, 0, stream>>>(x, degp, esrc, out,
                                           W0, W1, gamma, beta, ew);
}